// Round 1
// baseline (5080.070 us; speedup 1.0000x reference)
//
#include <hip/hip_runtime.h>

#define N_NODES 1000
#define BATCH 16
#define SEQ 12
#define HDIM 64
#define IN_DIM 3
#define E_EDGES 16000
#define EN (E_EDGES + N_NODES)
#define NB (N_NODES * BATCH)

__device__ __forceinline__ float sigmoidf(float x) { return 1.0f / (1.0f + expf(-x)); }

// ---------------------------------------------------------------------------
// prep: copy carries into ws, pack M (64x384), fpred[n], zero prev
// ---------------------------------------------------------------------------
__global__ void prep_kernel(const float* __restrict__ hidden0,
                            const float* __restrict__ hidden1,
                            const float* __restrict__ features,
                            const float* __restrict__ W3,
                            const float* __restrict__ b3,
                            const float* __restrict__ Wo,
                            const float* __restrict__ bo,
                            float* __restrict__ h0, float* __restrict__ h1,
                            float* __restrict__ M, float* __restrict__ fpred,
                            float* __restrict__ prev)
{
    int tid = blockIdx.x * blockDim.x + threadIdx.x;
    int stride = gridDim.x * blockDim.x;

    for (int i = tid; i < NB * HDIM; i += stride) { h0[i] = hidden0[i]; h1[i] = hidden1[i]; }

    // M[k*384 + c]: c in [0,384): grp = c/64, h = c%64
    // grp0: W3[(k*64+h)*2+0], grp1: W3[(k*64+h)*2+1], grp2: b3[k*64+h]
    // grp3: W3[((64+k)*64+h)*2+0], grp4: W3[((64+k)*64+h)*2+1], grp5: b3[(64+k)*64+h]
    for (int i = tid; i < 64 * 384; i += stride) {
        int k = i / 384, c = i % 384;
        int grp = c / 64, h = c % 64;
        int kk = (grp < 3 ? k : 64 + k) * 64 + h;
        float val;
        if (grp == 0 || grp == 3)      val = W3[kk * 2 + 0];
        else if (grp == 1 || grp == 4) val = W3[kk * 2 + 1];
        else                           val = b3[kk];
        M[i] = val;
    }

    for (int i = tid; i < NB; i += stride) prev[i] = 0.0f;

    for (int n = tid; n < N_NODES; n += stride) {
        float acc = bo[0];
        for (int h = 0; h < HDIM; ++h) acc += features[n * HDIM + h] * Wo[64 + h];
        fpred[n] = acc;
    }
}

// ---------------------------------------------------------------------------
// edge MLP: u,v per edge (runs once per launch)
// ---------------------------------------------------------------------------
__global__ __launch_bounds__(64) void edge_mlp_kernel(const int* __restrict__ edge_index,
                                                      const float* __restrict__ features,
                                                      const float* __restrict__ W1,
                                                      const float* __restrict__ b1,
                                                      const float* __restrict__ W2,
                                                      const float* __restrict__ b2,
                                                      float* __restrict__ uv)
{
    int e = blockIdx.x;
    int s, d;
    if (e < E_EDGES) { s = edge_index[e]; d = edge_index[E_EDGES + e]; }
    else             { s = e - E_EDGES; d = s; }

    __shared__ float ft[128];
    __shared__ float w1s[16];
    int t = threadIdx.x;
    ft[t]      = features[d * HDIM + t];  // dst first
    ft[64 + t] = features[s * HDIM + t];
    __syncthreads();
    if (t < 16) {
        float acc = b1[t];
        #pragma unroll 8
        for (int k = 0; k < 128; ++k) acc += ft[k] * W1[t * 128 + k];
        w1s[t] = sigmoidf(acc);
    }
    __syncthreads();
    if (t < 2) {
        float acc = b2[t];
        #pragma unroll
        for (int k = 0; k < 16; ++k) acc += w1s[k] * W2[t * 16 + k];
        uv[e * 2 + t] = sigmoidf(acc);
    }
}

// ---------------------------------------------------------------------------
// GRU1 (in-place on h0) + projection P = h0n @ M.  4 rows per 256-thr block.
// ---------------------------------------------------------------------------
__global__ __launch_bounds__(256) void gru1_proj_kernel(const float* __restrict__ labels,
                                                        const float* __restrict__ prev,
                                                        const float* __restrict__ Wi1,
                                                        const float* __restrict__ Wh1,
                                                        const float* __restrict__ bi1,
                                                        const float* __restrict__ bh1,
                                                        const float* __restrict__ M,
                                                        float* __restrict__ h0,
                                                        float* __restrict__ P,
                                                        int t)
{
    int r = threadIdx.x >> 6;
    int j = threadIdx.x & 63;
    int row = blockIdx.x * 4 + r;     // row = n*B + b

    __shared__ float hs[4][64];
    __shared__ float hn[4][64];

    float hj = h0[row * HDIM + j];
    hs[r][j] = hj;
    __syncthreads();

    float x0 = 0.f, x1 = 0.f, x2 = 0.f;
    if (t > 0) {
        x0 = prev[row];
        const float* lab = labels + (row * SEQ + (t - 1)) * IN_DIM;
        x1 = lab[1];
        x2 = lab[2];
    }

    float gi_r = bi1[j]        + x0 * Wi1[j * 3]          + x1 * Wi1[j * 3 + 1]          + x2 * Wi1[j * 3 + 2];
    float gi_z = bi1[64 + j]   + x0 * Wi1[(64 + j) * 3]   + x1 * Wi1[(64 + j) * 3 + 1]   + x2 * Wi1[(64 + j) * 3 + 2];
    float gi_n = bi1[128 + j]  + x0 * Wi1[(128 + j) * 3]  + x1 * Wi1[(128 + j) * 3 + 1]  + x2 * Wi1[(128 + j) * 3 + 2];

    float gh_r = bh1[j], gh_z = bh1[64 + j], gh_n = bh1[128 + j];
    #pragma unroll 8
    for (int k = 0; k < 64; ++k) {
        float hk = hs[r][k];
        gh_r += Wh1[j * 64 + k] * hk;
        gh_z += Wh1[(64 + j) * 64 + k] * hk;
        gh_n += Wh1[(128 + j) * 64 + k] * hk;
    }

    float rg = sigmoidf(gi_r + gh_r);
    float zg = sigmoidf(gi_z + gh_z);
    float ng = tanhf(gi_n + rg * gh_n);
    float hnew = (1.0f - zg) * ng + zg * hj;

    h0[row * HDIM + j] = hnew;
    hn[r][j] = hnew;
    __syncthreads();

    float acc0 = 0.f, acc1 = 0.f, acc2 = 0.f, acc3 = 0.f, acc4 = 0.f, acc5 = 0.f;
    #pragma unroll 8
    for (int k = 0; k < 64; ++k) {
        float hk = hn[r][k];
        const float* mrow = M + k * 384;
        acc0 += hk * mrow[j];
        acc1 += hk * mrow[64 + j];
        acc2 += hk * mrow[128 + j];
        acc3 += hk * mrow[192 + j];
        acc4 += hk * mrow[256 + j];
        acc5 += hk * mrow[320 + j];
    }
    float* prow = P + row * 384;
    prow[j]        = acc0;
    prow[64 + j]   = acc1;
    prow[128 + j]  = acc2;
    prow[192 + j]  = acc3;
    prow[256 + j]  = acc4;
    prow[320 + j]  = acc5;
}

// ---------------------------------------------------------------------------
// edge step: alpha -> leaky_relu -> softmax over b (thread-local) -> atomic agg
// one block per edge, thread = h, loop b in registers
// ---------------------------------------------------------------------------
__global__ __launch_bounds__(64) void edge_step_kernel(const int* __restrict__ edge_index,
                                                       const float* __restrict__ uv,
                                                       const float* __restrict__ P,
                                                       const float* __restrict__ h0,
                                                       float* __restrict__ agg)
{
    int e = blockIdx.x;
    int s, d;
    if (e < E_EDGES) { s = edge_index[e]; d = edge_index[E_EDGES + e]; }
    else             { s = e - E_EDGES; d = s; }

    float u = uv[e * 2];
    float v = uv[e * 2 + 1];
    int h = threadIdx.x;

    float al[BATCH], stj[BATCH];
    #pragma unroll
    for (int b = 0; b < BATCH; ++b) {
        const float* pd = P + (d * BATCH + b) * 384;
        const float* ps = P + (s * BATCH + b) * 384;
        float a = u * (pd[h] + ps[192 + h]) + v * (pd[64 + h] + ps[256 + h])
                + pd[128 + h] + ps[320 + h];
        al[b] = (a > 0.0f) ? a : 0.01f * a;
        stj[b] = h0[(s * BATCH + b) * HDIM + h];
    }

    float m = al[0];
    #pragma unroll
    for (int b = 1; b < BATCH; ++b) m = fmaxf(m, al[b]);
    float sum = 0.0f;
    #pragma unroll
    for (int b = 0; b < BATCH; ++b) { al[b] = expf(al[b] - m); sum += al[b]; }
    float inv = 1.0f / sum;
    #pragma unroll
    for (int b = 0; b < BATCH; ++b) {
        atomicAdd(&agg[(d * BATCH + b) * HDIM + h], al[b] * inv * stj[b]);
    }
}

// ---------------------------------------------------------------------------
// GRU2 (in-place on h1) with relu(agg) input + output projection
// ---------------------------------------------------------------------------
__global__ __launch_bounds__(256) void gru2_pred_kernel(const float* __restrict__ agg,
                                                        const float* __restrict__ Wi2,
                                                        const float* __restrict__ Wh2,
                                                        const float* __restrict__ bi2,
                                                        const float* __restrict__ bh2,
                                                        const float* __restrict__ Wo,
                                                        const float* __restrict__ fpred,
                                                        float* __restrict__ h1,
                                                        float* __restrict__ prev,
                                                        float* __restrict__ out,
                                                        int t)
{
    int r = threadIdx.x >> 6;
    int j = threadIdx.x & 63;
    int row = blockIdx.x * 4 + r;   // row = n*B + b

    __shared__ float gs[4][64];
    __shared__ float hs[4][64];

    float g = agg[row * HDIM + j];
    g = (g > 0.0f) ? g : 0.0f;      // relu
    float hj = h1[row * HDIM + j];
    gs[r][j] = g;
    hs[r][j] = hj;
    __syncthreads();

    float gi_r = bi2[j], gi_z = bi2[64 + j], gi_n = bi2[128 + j];
    float gh_r = bh2[j], gh_z = bh2[64 + j], gh_n = bh2[128 + j];
    #pragma unroll 8
    for (int k = 0; k < 64; ++k) {
        float gk = gs[r][k];
        float hk = hs[r][k];
        gi_r += Wi2[j * 64 + k] * gk;
        gi_z += Wi2[(64 + j) * 64 + k] * gk;
        gi_n += Wi2[(128 + j) * 64 + k] * gk;
        gh_r += Wh2[j * 64 + k] * hk;
        gh_z += Wh2[(64 + j) * 64 + k] * hk;
        gh_n += Wh2[(128 + j) * 64 + k] * hk;
    }

    float rg = sigmoidf(gi_r + gh_r);
    float zg = sigmoidf(gi_z + gh_z);
    float ng = tanhf(gi_n + rg * gh_n);
    float hnew = (1.0f - zg) * ng + zg * hj;

    h1[row * HDIM + j] = hnew;

    // pred = dot(h1n_row, Wo[0:64]) + fpred[n]
    float part = hnew * Wo[j];
    #pragma unroll
    for (int off = 32; off > 0; off >>= 1) part += __shfl_down(part, off, 64);
    if (j == 0) {
        float p = part + fpred[row / BATCH];
        prev[row] = p;
        out[row * SEQ + t] = p;   // out[n][b][t][0]
    }
}

// ---------------------------------------------------------------------------
extern "C" void kernel_launch(void* const* d_in, const int* in_sizes, int n_in,
                              void* d_out, int out_size, void* d_ws, size_t ws_size,
                              hipStream_t stream)
{
    const float* hidden0  = (const float*)d_in[0];
    const float* hidden1  = (const float*)d_in[1];
    const float* features = (const float*)d_in[2];
    const float* labels   = (const float*)d_in[3];
    const int*   edge_idx = (const int*)d_in[4];
    const float* Wi1 = (const float*)d_in[5];
    const float* Wh1 = (const float*)d_in[6];
    const float* bi1 = (const float*)d_in[7];
    const float* bh1 = (const float*)d_in[8];
    const float* W1  = (const float*)d_in[9];
    const float* b1  = (const float*)d_in[10];
    const float* W2  = (const float*)d_in[11];
    const float* b2  = (const float*)d_in[12];
    const float* W3  = (const float*)d_in[13];
    const float* b3  = (const float*)d_in[14];
    const float* Wi2 = (const float*)d_in[15];
    const float* Wh2 = (const float*)d_in[16];
    const float* bi2 = (const float*)d_in[17];
    const float* bh2 = (const float*)d_in[18];
    const float* Wo  = (const float*)d_in[19];
    const float* bo  = (const float*)d_in[20];

    float* ws = (float*)d_ws;
    float* h0    = ws;                 ws += NB * HDIM;        // 1,024,000
    float* h1    = ws;                 ws += NB * HDIM;        // 1,024,000
    float* P     = ws;                 ws += NB * 384;         // 6,144,000
    float* agg   = ws;                 ws += NB * HDIM;        // 1,024,000
    float* uv    = ws;                 ws += EN * 2;           // 34,000
    float* M     = ws;                 ws += 64 * 384;         // 24,576
    float* fpred = ws;                 ws += N_NODES;          // 1,000
    float* prev  = ws;                 ws += NB;               // 16,000
    float* out   = (float*)d_out;

    prep_kernel<<<256, 256, 0, stream>>>(hidden0, hidden1, features, W3, b3, Wo, bo,
                                         h0, h1, M, fpred, prev);
    edge_mlp_kernel<<<EN, 64, 0, stream>>>(edge_idx, features, W1, b1, W2, b2, uv);

    for (int t = 0; t < SEQ; ++t) {
        gru1_proj_kernel<<<NB / 4, 256, 0, stream>>>(labels, prev, Wi1, Wh1, bi1, bh1,
                                                     M, h0, P, t);
        hipMemsetAsync(agg, 0, (size_t)NB * HDIM * sizeof(float), stream);
        edge_step_kernel<<<EN, 64, 0, stream>>>(edge_idx, uv, P, h0, agg);
        gru2_pred_kernel<<<NB / 4, 256, 0, stream>>>(agg, Wi2, Wh2, bi2, bh2, Wo, fpred,
                                                     h1, prev, out, t);
    }
}

// Round 2
// 1980.100 us; speedup vs baseline: 2.5656x; 2.5656x over previous
//
#include <hip/hip_runtime.h>

#define N_NODES 1000
#define BATCH 16
#define SEQ 12
#define IN_DIM 3
#define HDIM 64
#define E_EDGES 16000
#define EN (E_EDGES + N_NODES)
#define NB (N_NODES * BATCH)

typedef unsigned int u32;
typedef unsigned short u16;

__device__ __forceinline__ float sigmoidf(float x) { return 1.0f / (1.0f + expf(-x)); }

__device__ __forceinline__ u16 f2bf(float x) {
    u32 u = __builtin_bit_cast(u32, x);
    u32 r = (u + 0x7fffu + ((u >> 16) & 1u)) >> 16;
    return (u16)r;
}
__device__ __forceinline__ float bf2f(u32 h) {
    return __builtin_bit_cast(float, (h & 0xffffu) << 16);
}
__device__ __forceinline__ u32 pack2(float a, float b) {
    return (u32)f2bf(a) | ((u32)f2bf(b) << 16);
}

// ---------------------------------------------------------------------------
// prep: copy carries, pack M (64x384), transpose weights, fpred, zero prev
// ---------------------------------------------------------------------------
__global__ void prep_kernel(const float* __restrict__ hidden0,
                            const float* __restrict__ hidden1,
                            const float* __restrict__ features,
                            const float* __restrict__ W3,
                            const float* __restrict__ b3,
                            const float* __restrict__ Wo,
                            const float* __restrict__ bo,
                            const float* __restrict__ Wh1,
                            const float* __restrict__ Wi1,
                            const float* __restrict__ Wi2,
                            const float* __restrict__ Wh2,
                            float* __restrict__ h0, float* __restrict__ h1,
                            float* __restrict__ M,
                            float* __restrict__ Wh1T, float* __restrict__ Wi1T,
                            float* __restrict__ Wi2T, float* __restrict__ Wh2T,
                            float* __restrict__ fpred, float* __restrict__ prev)
{
    int tid = blockIdx.x * blockDim.x + threadIdx.x;
    int stride = gridDim.x * blockDim.x;

    for (int i = tid; i < NB * HDIM; i += stride) { h0[i] = hidden0[i]; h1[i] = hidden1[i]; }

    // M[k*384 + grp*64 + h]:
    // grp0: W3[(k*64+h)*2+0], grp1: +1, grp2: b3[k*64+h]
    // grp3: W3[((64+k)*64+h)*2+0], grp4: +1, grp5: b3[(64+k)*64+h]
    for (int i = tid; i < 64 * 384; i += stride) {
        int k = i / 384, c = i % 384;
        int grp = c / 64, h = c % 64;
        int kk = (grp < 3 ? k : 64 + k) * 64 + h;
        float val;
        if (grp == 0 || grp == 3)      val = W3[kk * 2 + 0];
        else if (grp == 1 || grp == 4) val = W3[kk * 2 + 1];
        else                           val = b3[kk];
        M[i] = val;
    }

    // weight transposes: T[k*192 + gj] = W[gj*64 + k]
    for (int i = tid; i < 192 * 64; i += stride) {
        int k = i / 192, gj = i % 192;
        Wh1T[i] = Wh1[gj * 64 + k];
        Wi2T[i] = Wi2[gj * 64 + k];
        Wh2T[i] = Wh2[gj * 64 + k];
    }
    // Wi1T[c*192 + gj] = Wi1[gj*3 + c]
    for (int i = tid; i < 3 * 192; i += stride) {
        int c = i / 192, gj = i % 192;
        Wi1T[i] = Wi1[gj * 3 + c];
    }

    for (int i = tid; i < NB; i += stride) prev[i] = 0.0f;

    for (int n = tid; n < N_NODES; n += stride) {
        float acc = bo[0];
        for (int h = 0; h < HDIM; ++h) acc += features[n * HDIM + h] * Wo[64 + h];
        fpred[n] = acc;
    }
}

// ---------------------------------------------------------------------------
// edge MLP: u,v per edge (runs once). 4 edges per 256-thread block.
// ---------------------------------------------------------------------------
__global__ __launch_bounds__(256) void edge_mlp_kernel(const int* __restrict__ edge_index,
                                                       const float* __restrict__ features,
                                                       const float* __restrict__ W1,
                                                       const float* __restrict__ b1,
                                                       const float* __restrict__ W2,
                                                       const float* __restrict__ b2,
                                                       float* __restrict__ uv)
{
    int w = threadIdx.x >> 6, j = threadIdx.x & 63;
    int e = blockIdx.x * 4 + w;
    int s, d;
    if (e < E_EDGES) { s = edge_index[e]; d = edge_index[E_EDGES + e]; }
    else             { s = e - E_EDGES; d = s; }

    __shared__ float ft[4][128];
    __shared__ float w1s[4][16];
    ft[w][j]      = features[d * HDIM + j];   // dst half first
    ft[w][64 + j] = features[s * HDIM + j];
    __syncthreads();

    int o = j & 15, part = j >> 4;
    float acc = 0.0f;
    #pragma unroll 8
    for (int kk = 0; kk < 32; ++kk)
        acc += ft[w][part * 32 + kk] * W1[o * 128 + part * 32 + kk];
    acc += __shfl_xor(acc, 16, 64);
    acc += __shfl_xor(acc, 32, 64);
    if (j < 16) w1s[w][j] = sigmoidf(acc + b1[j]);
    __syncthreads();
    if (j < 2) {
        float a2 = b2[j];
        #pragma unroll
        for (int k = 0; k < 16; ++k) a2 += w1s[w][k] * W2[j * 16 + k];
        uv[e * 2 + j] = sigmoidf(a2);
    }
}

// ---------------------------------------------------------------------------
// GRU1 (in-place h0) + projection. 16 rows/block, 4 rows per wave,
// register-blocked: each thread owns column j of 4 rows.
// Writes Pd (bf16: c0,c1 | c2,pad) and Ps (bf16: c3,c4 | c5,h0n).
// ---------------------------------------------------------------------------
__global__ __launch_bounds__(256) void gru1_proj_kernel(const float* __restrict__ labels,
                                                        const float* __restrict__ prev,
                                                        const float* __restrict__ Wi1T,
                                                        const float* __restrict__ Wh1T,
                                                        const float* __restrict__ bi1,
                                                        const float* __restrict__ bh1,
                                                        const float* __restrict__ M,
                                                        float* __restrict__ h0,
                                                        uint2* __restrict__ Pd,
                                                        uint2* __restrict__ Ps,
                                                        int t)
{
    int w = threadIdx.x >> 6, j = threadIdx.x & 63;
    int rbase = blockIdx.x * 16 + w * 4;
    __shared__ float hs[16][64];   // each wave only touches its own 4 rows

    #pragma unroll
    for (int rr = 0; rr < 4; ++rr)
        hs[w * 4 + rr][j] = h0[(size_t)(rbase + rr) * HDIM + j];

    float ar[4], az[4], an[4];
    {
        float br = bh1[j], bz = bh1[64 + j], bn = bh1[128 + j];
        #pragma unroll
        for (int rr = 0; rr < 4; ++rr) { ar[rr] = br; az[rr] = bz; an[rr] = bn; }
    }

    for (int k4 = 0; k4 < 64; k4 += 4) {
        float4 h4[4];
        #pragma unroll
        for (int rr = 0; rr < 4; ++rr) h4[rr] = *(const float4*)&hs[w * 4 + rr][k4];
        #pragma unroll
        for (int kk = 0; kk < 4; ++kk) {
            const float* wrow = &Wh1T[(k4 + kk) * 192 + j];
            float wr = wrow[0], wz = wrow[64], wn = wrow[128];
            #pragma unroll
            for (int rr = 0; rr < 4; ++rr) {
                float hk = ((const float*)&h4[rr])[kk];
                ar[rr] += wr * hk; az[rr] += wz * hk; an[rr] += wn * hk;
            }
        }
    }

    // input-gate weights for this column j (reused over 4 rows)
    float wi00 = Wi1T[j],       wi01 = Wi1T[64 + j],       wi02 = Wi1T[128 + j];
    float wi10 = Wi1T[192 + j], wi11 = Wi1T[192 + 64 + j], wi12 = Wi1T[192 + 128 + j];
    float wi20 = Wi1T[384 + j], wi21 = Wi1T[384 + 64 + j], wi22 = Wi1T[384 + 128 + j];
    float bir = bi1[j], biz = bi1[64 + j], bin_ = bi1[128 + j];

    float hnew[4];
    #pragma unroll
    for (int rr = 0; rr < 4; ++rr) {
        int row = rbase + rr;
        float x0 = 0.f, x1 = 0.f, x2 = 0.f;
        if (t > 0) {
            x0 = prev[row];
            const float* lab = labels + ((size_t)row * SEQ + (t - 1)) * IN_DIM;
            x1 = lab[1]; x2 = lab[2];
        }
        float gir = bir  + x0 * wi00 + x1 * wi10 + x2 * wi20;
        float giz = biz  + x0 * wi01 + x1 * wi11 + x2 * wi21;
        float gin = bin_ + x0 * wi02 + x1 * wi12 + x2 * wi22;
        float rg = sigmoidf(gir + ar[rr]);
        float zg = sigmoidf(giz + az[rr]);
        float ng = tanhf(gin + rg * an[rr]);
        float hj = hs[w * 4 + rr][j];
        hnew[rr] = (1.0f - zg) * ng + zg * hj;
    }

    #pragma unroll
    for (int rr = 0; rr < 4; ++rr) {
        hs[w * 4 + rr][j] = hnew[rr];
        h0[(size_t)(rbase + rr) * HDIM + j] = hnew[rr];
    }

    // projection: P = h0n @ M, 6 components per (row, j)
    float a0[4] = {0,0,0,0}, a1[4] = {0,0,0,0}, a2[4] = {0,0,0,0};
    float a3[4] = {0,0,0,0}, a4[4] = {0,0,0,0}, a5[4] = {0,0,0,0};
    for (int k4 = 0; k4 < 64; k4 += 4) {
        float4 h4[4];
        #pragma unroll
        for (int rr = 0; rr < 4; ++rr) h4[rr] = *(const float4*)&hs[w * 4 + rr][k4];
        #pragma unroll
        for (int kk = 0; kk < 4; ++kk) {
            const float* mrow = &M[(size_t)(k4 + kk) * 384 + j];
            float m0 = mrow[0],   m1 = mrow[64],  m2 = mrow[128];
            float m3 = mrow[192], m4 = mrow[256], m5 = mrow[320];
            #pragma unroll
            for (int rr = 0; rr < 4; ++rr) {
                float hk = ((const float*)&h4[rr])[kk];
                a0[rr] += m0 * hk; a1[rr] += m1 * hk; a2[rr] += m2 * hk;
                a3[rr] += m3 * hk; a4[rr] += m4 * hk; a5[rr] += m5 * hk;
            }
        }
    }
    #pragma unroll
    for (int rr = 0; rr < 4; ++rr) {
        size_t row = rbase + rr;
        Pd[row * 64 + j] = make_uint2(pack2(a0[rr], a1[rr]), pack2(a2[rr], 0.f));
        Ps[row * 64 + j] = make_uint2(pack2(a3[rr], a4[rr]), pack2(a5[rr], hnew[rr]));
    }
}

// ---------------------------------------------------------------------------
// edge step: alpha -> leaky -> softmax over b (thread-local) -> atomic agg.
// 4 edges per 256-thread block; thread = h; b loop in registers.
// ---------------------------------------------------------------------------
__global__ __launch_bounds__(256) void edge_step_kernel(const int* __restrict__ edge_index,
                                                        const float* __restrict__ uv,
                                                        const uint2* __restrict__ Pd,
                                                        const uint2* __restrict__ Ps,
                                                        float* __restrict__ agg)
{
    int e = blockIdx.x * 4 + (threadIdx.x >> 6);
    int h = threadIdx.x & 63;
    int s, d;
    if (e < E_EDGES) { s = edge_index[e]; d = edge_index[E_EDGES + e]; }
    else             { s = e - E_EDGES; d = s; }

    float u = uv[e * 2], v = uv[e * 2 + 1];

    float al[BATCH], stj[BATCH];
    #pragma unroll
    for (int b = 0; b < BATCH; ++b) {
        uint2 pd = Pd[((size_t)d * BATCH + b) * 64 + h];
        uint2 ps = Ps[((size_t)s * BATCH + b) * 64 + h];
        float c0 = bf2f(pd.x), c1 = bf2f(pd.x >> 16), c2 = bf2f(pd.y);
        float c3 = bf2f(ps.x), c4 = bf2f(ps.x >> 16), c5 = bf2f(ps.y);
        float a = u * (c0 + c3) + v * (c1 + c4) + c2 + c5;
        al[b] = (a > 0.0f) ? a : 0.01f * a;
        stj[b] = bf2f(ps.y >> 16);
    }

    float m = al[0];
    #pragma unroll
    for (int b = 1; b < BATCH; ++b) m = fmaxf(m, al[b]);
    float sum = 0.0f;
    #pragma unroll
    for (int b = 0; b < BATCH; ++b) { al[b] = expf(al[b] - m); sum += al[b]; }
    float inv = 1.0f / sum;

    float* arow = &agg[(size_t)d * BATCH * HDIM + h];
    #pragma unroll
    for (int b = 0; b < BATCH; ++b)
        atomicAdd(arow + b * HDIM, al[b] * inv * stj[b]);
}

// ---------------------------------------------------------------------------
// GRU2 (in-place h1) + output projection. 16 rows/block, register-blocked.
// ---------------------------------------------------------------------------
__global__ __launch_bounds__(256) void gru2_pred_kernel(const float* __restrict__ agg,
                                                        const float* __restrict__ Wi2T,
                                                        const float* __restrict__ Wh2T,
                                                        const float* __restrict__ bi2,
                                                        const float* __restrict__ bh2,
                                                        const float* __restrict__ Wo,
                                                        const float* __restrict__ fpred,
                                                        float* __restrict__ h1,
                                                        float* __restrict__ prev,
                                                        float* __restrict__ out,
                                                        int t)
{
    int w = threadIdx.x >> 6, j = threadIdx.x & 63;
    int rbase = blockIdx.x * 16 + w * 4;
    __shared__ float gs[16][64];
    __shared__ float hs[16][64];

    #pragma unroll
    for (int rr = 0; rr < 4; ++rr) {
        float g = agg[(size_t)(rbase + rr) * HDIM + j];
        gs[w * 4 + rr][j] = fmaxf(g, 0.0f);   // relu
        hs[w * 4 + rr][j] = h1[(size_t)(rbase + rr) * HDIM + j];
    }

    float air[4], aiz[4], ain[4], ahr[4], ahz[4], ahn[4];
    {
        float b0 = bi2[j], b1 = bi2[64 + j], b2 = bi2[128 + j];
        float c0 = bh2[j], c1 = bh2[64 + j], c2 = bh2[128 + j];
        #pragma unroll
        for (int rr = 0; rr < 4; ++rr) {
            air[rr] = b0; aiz[rr] = b1; ain[rr] = b2;
            ahr[rr] = c0; ahz[rr] = c1; ahn[rr] = c2;
        }
    }

    for (int k4 = 0; k4 < 64; k4 += 4) {
        float4 g4[4], h4[4];
        #pragma unroll
        for (int rr = 0; rr < 4; ++rr) {
            g4[rr] = *(const float4*)&gs[w * 4 + rr][k4];
            h4[rr] = *(const float4*)&hs[w * 4 + rr][k4];
        }
        #pragma unroll
        for (int kk = 0; kk < 4; ++kk) {
            const float* wiRow = &Wi2T[(k4 + kk) * 192 + j];
            const float* whRow = &Wh2T[(k4 + kk) * 192 + j];
            float wir = wiRow[0], wiz = wiRow[64], win = wiRow[128];
            float whr = whRow[0], whz = whRow[64], whn = whRow[128];
            #pragma unroll
            for (int rr = 0; rr < 4; ++rr) {
                float gk = ((const float*)&g4[rr])[kk];
                float hk = ((const float*)&h4[rr])[kk];
                air[rr] += wir * gk; aiz[rr] += wiz * gk; ain[rr] += win * gk;
                ahr[rr] += whr * hk; ahz[rr] += whz * hk; ahn[rr] += whn * hk;
            }
        }
    }

    float woj = Wo[j];
    #pragma unroll
    for (int rr = 0; rr < 4; ++rr) {
        float rg = sigmoidf(air[rr] + ahr[rr]);
        float zg = sigmoidf(aiz[rr] + ahz[rr]);
        float ng = tanhf(ain[rr] + rg * ahn[rr]);
        float hj = hs[w * 4 + rr][j];
        float hn = (1.0f - zg) * ng + zg * hj;
        h1[(size_t)(rbase + rr) * HDIM + j] = hn;

        float part = hn * woj;
        #pragma unroll
        for (int off = 32; off; off >>= 1) part += __shfl_xor(part, off, 64);
        if (j == rr) {
            int row = rbase + rr;
            float p = part + fpred[row / BATCH];
            prev[row] = p;
            out[(size_t)row * SEQ + t] = p;   // out[n][b][t][0]
        }
    }
}

// ---------------------------------------------------------------------------
extern "C" void kernel_launch(void* const* d_in, const int* in_sizes, int n_in,
                              void* d_out, int out_size, void* d_ws, size_t ws_size,
                              hipStream_t stream)
{
    const float* hidden0  = (const float*)d_in[0];
    const float* hidden1  = (const float*)d_in[1];
    const float* features = (const float*)d_in[2];
    const float* labels   = (const float*)d_in[3];
    const int*   edge_idx = (const int*)d_in[4];
    const float* Wi1 = (const float*)d_in[5];
    const float* Wh1 = (const float*)d_in[6];
    const float* bi1 = (const float*)d_in[7];
    const float* bh1 = (const float*)d_in[8];
    const float* W1  = (const float*)d_in[9];
    const float* b1  = (const float*)d_in[10];
    const float* W2  = (const float*)d_in[11];
    const float* b2  = (const float*)d_in[12];
    const float* W3  = (const float*)d_in[13];
    const float* b3  = (const float*)d_in[14];
    const float* Wi2 = (const float*)d_in[15];
    const float* Wh2 = (const float*)d_in[16];
    const float* bi2 = (const float*)d_in[17];
    const float* bh2 = (const float*)d_in[18];
    const float* Wo  = (const float*)d_in[19];
    const float* bo  = (const float*)d_in[20];

    float* ws = (float*)d_ws;
    float* h0    = ws;  ws += NB * HDIM;
    float* h1    = ws;  ws += NB * HDIM;
    uint2* Pd    = (uint2*)ws;  ws += NB * HDIM * 2;   // uint2 per (row,h)
    uint2* Ps    = (uint2*)ws;  ws += NB * HDIM * 2;
    float* agg   = ws;  ws += NB * HDIM;
    float* uv    = ws;  ws += EN * 2;
    float* M     = ws;  ws += 64 * 384;
    float* Wh1T  = ws;  ws += 64 * 192;
    float* Wi1T  = ws;  ws += 3 * 192;
    float* Wi2T  = ws;  ws += 64 * 192;
    float* Wh2T  = ws;  ws += 64 * 192;
    float* fpred = ws;  ws += N_NODES;
    float* prev  = ws;  ws += NB;
    float* out   = (float*)d_out;

    prep_kernel<<<256, 256, 0, stream>>>(hidden0, hidden1, features, W3, b3, Wo, bo,
                                         Wh1, Wi1, Wi2, Wh2,
                                         h0, h1, M, Wh1T, Wi1T, Wi2T, Wh2T, fpred, prev);
    edge_mlp_kernel<<<(EN + 3) / 4, 256, 0, stream>>>(edge_idx, features, W1, b1, W2, b2, uv);

    for (int t = 0; t < SEQ; ++t) {
        gru1_proj_kernel<<<NB / 16, 256, 0, stream>>>(labels, prev, Wi1T, Wh1T, bi1, bh1,
                                                      M, h0, Pd, Ps, t);
        hipMemsetAsync(agg, 0, (size_t)NB * HDIM * sizeof(float), stream);
        edge_step_kernel<<<EN / 4, 256, 0, stream>>>(edge_idx, uv, Pd, Ps, agg);
        gru2_pred_kernel<<<NB / 16, 256, 0, stream>>>(agg, Wi2T, Wh2T, bi2, bh2, Wo, fpred,
                                                      h1, prev, out, t);
    }
}